// Round 9
// baseline (947.517 us; speedup 1.0000x reference)
//
#include <hip/hip_runtime.h>
#include <hip/hip_bf16.h>
#include <float.h>

#define DEV __device__ __forceinline__

using f32x4 = __attribute__((ext_vector_type(4))) float;
using f4v   = __attribute__((ext_vector_type(4))) float;
using bfrag = __attribute__((ext_vector_type(8))) short;     // 8 bf16
using hfrag = __attribute__((ext_vector_type(8))) _Float16;  // 8 f16
using us8   = __attribute__((ext_vector_type(8))) unsigned short;

DEV unsigned short f2bf(float f) {
  unsigned u = __builtin_bit_cast(unsigned, f);
  u += 0x7FFFu + ((u >> 16) & 1u);
  return (unsigned short)(u >> 16);
}
DEV float bf2f(unsigned short h) {
  unsigned u = ((unsigned)h) << 16;
  return __builtin_bit_cast(float, u);
}
DEV f32x4 mfma_bf(bfrag a, bfrag b, f32x4 c) {
  return __builtin_amdgcn_mfma_f32_16x16x32_bf16(a, b, c, 0, 0, 0);
}
DEV f32x4 mfma_h(hfrag a, hfrag b, f32x4 c) {
  return __builtin_amdgcn_mfma_f32_16x16x32_f16(a, b, c, 0, 0, 0);
}
DEV float readlane_f(float v, int l) {
  return __builtin_bit_cast(float,
      __builtin_amdgcn_readlane(__builtin_bit_cast(int, v), l));
}
// async global->LDS, 16B per lane; LDS dest must be wave-uniform base + lane*16
DEV void glds16(const void* g, void* l) {
  __builtin_amdgcn_global_load_lds(
      (const __attribute__((address_space(1))) void*)g,
      (__attribute__((address_space(3))) void*)l, 16, 0, 0);
}
template<int BYTES>
DEV void gldsN(const char* __restrict__ g, char* __restrict__ l, int tid) {
  if constexpr (BYTES >= 8192) {
#pragma unroll
    for (int o = 0; o < BYTES; o += 8192)
      glds16(g + o + tid * 16, l + o + tid * 16);
  } else {
    if (tid * 16 < BYTES) glds16(g + tid * 16, l + tid * 16);  // full waves only
  }
}

// XOR-swizzled LDS byte offset for row-major tiles of RB bytes/row (T2 pattern)
template<int RB>
DEV unsigned swz(int row, int colb) {
  return (unsigned)(row * RB) +
         (((unsigned)colb) ^ (((unsigned)(row << 4)) & (unsigned)(RB - 1)));
}
template<int RB>
DEV bfrag ldfragB(const unsigned short* base, int row, int kcol) {
  return *(const bfrag*)((const char*)base + swz<RB>(row, kcol * 2));
}
template<int RB>
DEV hfrag ldfragH(const _Float16* base, int row, int kcol) {
  return *(const hfrag*)((const char*)base + swz<RB>(row, kcol * 2));
}

// full-wave bitonic sort, descending by value, ties ascending by index
DEV void bitonic64(float& v, int& ix, int lane) {
#pragma unroll
  for (int k = 2; k <= 64; k <<= 1) {
#pragma unroll
    for (int j = k >> 1; j > 0; j >>= 1) {
      const float ov = __shfl_xor(v, j);
      const int   oi = __shfl_xor(ix, j);
      const bool up = (lane & k) != 0;
      const bool iWin = (v > ov) || (v == ov && ix < oi);
      const bool keepBetter = (((lane & j) == 0) != up);
      if (iWin != keepBetter) { v = ov; ix = oi; }
    }
  }
}

// batch selector: b in 0..15 -> graph1 (xA) batches 0..7, graph2 (xB) 8..15
template<int C>
DEV const float* xbase(const float* xA, const float* xB, int b) {
  return (b < 8) ? xA + (size_t)b * 2048 * C
                 : xB + (size_t)(b - 8) * 2048 * C;
}

// ---------------- squared norms (16 batches, pair input) ----------------
template<int C>
__global__ __launch_bounds__(256)
void sq_kernel(const float* __restrict__ xA, const float* __restrict__ xB,
               float* __restrict__ sq) {
  const int i = blockIdx.x * 256 + threadIdx.x;   // 0 .. 16*2048-1
  const int b = i >> 11, n = i & 2047;
  const float* r = xbase<C>(xA, xB, b) + (size_t)n * C;
  float s = 0.f;
#pragma unroll
  for (int c = 0; c < C; c += 4) {
    f4v v = *(const f4v*)(r + c);
    s += v[0] * v[0] + v[1] * v[1] + v[2] * v[2] + v[3] * v[3];
  }
  sq[i] = s;
}

// ---------------- one-time fp32 -> bf16 hi/lo pre-swizzled tile images --------
// layout: [b(16)][tile(32)][ H: 64 rows x C32 bf16 swizzled | L: same ]
template<int C, int C32>
__global__ __launch_bounds__(256)
void cvt_kernel(const float* __restrict__ xA, const float* __restrict__ xB,
                char* __restrict__ xhl) {
  constexpr int CH8 = C32 / 8, RB = C32 * 2, HB = 64 * RB;
  const int idx = blockIdx.x * 256 + threadIdx.x;
  const int chunk = idx & (CH8 - 1);
  const int rg = idx / CH8;
  const int b = rg >> 11, n = rg & 2047;
  const float* src = xbase<C>(xA, xB, b) + (size_t)n * C;
  const int cb = chunk * 8;
  float f[8];
  if constexpr (C % 8 == 0) {
    *(f4v*)(f + 0) = *(const f4v*)(src + cb);
    *(f4v*)(f + 4) = *(const f4v*)(src + cb + 4);
  } else {
#pragma unroll
    for (int e = 0; e < 8; ++e) {
      const int c = cb + e;
      f[e] = (c < C) ? src[c] : 0.f;
    }
  }
  us8 hv, lv;
#pragma unroll
  for (int e = 0; e < 8; ++e) {
    const unsigned short hs = f2bf(f[e]);
    hv[e] = hs;
    lv[e] = f2bf(f[e] - bf2f(hs));
  }
  char* dst = xhl + (size_t)(b * 32 + (n >> 6)) * 2 * HB;
  const unsigned off = swz<RB>(n & 63, cb * 2);
  *(us8*)(dst + off) = hv;
  *(us8*)(dst + HB + off) = lv;
}

// ---------------- fused kNN: pipelined, 1 barrier/tile, lagged selection ------
// grid: b(16) x i-tile(64, 32 rows) = 1024 blocks, 512 threads (8 waves).
// body(t): issue async stage(t+1) -> XjC[(t+1)&1]; MFMA(t) -> S[t&1];
//          select(t-1) from S[(t-1)&1]; __syncthreads (drains vmcnt).
template<int C32>
__global__ __launch_bounds__(512)
void knn_kernel(const char* __restrict__ xhl, const float* __restrict__ sqg,
                int* __restrict__ idx_out) {
  constexpr int N = 2048, TI = 32, TJ = 64, TK = 20, NT = N / TJ;
  constexpr int RB = C32 * 2, HB = 64 * RB, TILEB = 2 * HB, HBi = TI * RB;
  const int b    = blockIdx.x >> 6;        // 0..15
  const int it   = blockIdx.x & 63;        // 32-row i-tile
  const int i0   = it * TI;
  const int tid  = threadIdx.x;
  const int lane = tid & 63;
  const int w    = tid >> 6;               // 0..7
  const int ri   = w >> 2;                 // 0..1
  const int ci   = w & 3;                  // 0..3

  __shared__ char XiC[2 * HBi];
  __shared__ char XjC[2][TILEB];
  __shared__ float S[2][TI][TJ + 4];

  const unsigned short* XiHp = (const unsigned short*)XiC;
  const unsigned short* XiLp = (const unsigned short*)(XiC + HBi);
  const int m15 = lane & 15, kb8 = (lane >> 4) * 8;

  const char* gbt = xhl + (size_t)(b * 32) * TILEB;
  const char* gti = gbt + (size_t)(i0 >> 6) * TILEB + (i0 & 63) * RB;
  gldsN<HBi>(gti, XiC, tid);            // Xi H slice (contiguous rows)
  gldsN<HBi>(gti + HB, XiC + HBi, tid); // Xi L slice
  gldsN<TILEB>(gbt, XjC[0], tid);       // tile 0
  float sq_cur = sqg[b * N + lane];     // sq of tile 0 (register)
  float sq_prev = 0.f;
  __syncthreads();                      // drains vmcnt: Xi + Xj0 staged

  // Xi fragments are loop-invariant -> registers
  bfrag ah[C32 / 32], al[C32 / 32];
#pragma unroll
  for (int ks = 0; ks < C32 / 32; ++ks) {
    ah[ks] = ldfragB<RB>(XiHp, 16 * ri + m15, ks * 32 + kb8);
    al[ks] = ldfragB<RB>(XiLp, 16 * ri + m15, ks * 32 + kb8);
  }

  float tv[4], t20[4]; int tix[4];
#pragma unroll
  for (int d = 0; d < 4; ++d) { tv[d] = -FLT_MAX; tix[d] = 0; t20[d] = -FLT_MAX; }

  // selection for tile jts (S buffer jts&1), sqv = sq of tile jts
  auto select_tile = [&](int jts, float sqv) {
    const int j0 = jts * TJ;
    const float (*Sb)[TJ + 4] = S[jts & 1];
#pragma unroll
    for (int d = 0; d < 4; ++d) {
      const float sc = 2.f * Sb[4 * w + d][lane] - sqv;
      if (jts == 0) {
        float v = sc; int ixv = lane;    // j0 == 0
        bitonic64(v, ixv, lane);
        tv[d]  = (lane < TK) ? v : -FLT_MAX;
        tix[d] = (lane < TK) ? ixv : 0;
        t20[d] = readlane_f(tv[d], TK - 1);
      } else {
        unsigned long long mm = __ballot(sc > t20[d]);
        if (mm) {
          while (mm) {
            const int src = __ffsll(mm) - 1;
            mm &= mm - 1;
            const float cv = readlane_f(sc, src);
            const int   ci2 = j0 + src;
            const float pv_ = __shfl_up(tv[d], 1);
            const int   pi_ = __shfl_up(tix[d], 1);
            const unsigned long long g =
                __ballot(tv[d] > cv || (tv[d] == cv && tix[d] < ci2));
            const int p = __popcll(g);     // wave-uniform
            float nv = (lane == p) ? cv  : ((lane > p) ? pv_ : tv[d]);
            int   ni = (lane == p) ? ci2 : ((lane > p) ? pi_ : tix[d]);
            tv[d]  = (lane >= TK) ? -FLT_MAX : nv;
            tix[d] = (lane >= TK) ? 0 : ni;
          }
          t20[d] = readlane_f(tv[d], TK - 1);  // refresh once per tile
        }
      }
    }
  };

  for (int jt = 0; jt < NT; ++jt) {
    float sq_next = 0.f;
    if (jt + 1 < NT) {   // issue next-tile stage early (hidden under MFMA+select)
      gldsN<TILEB>(gbt + (size_t)(jt + 1) * TILEB, XjC[(jt + 1) & 1], tid);
      sq_next = sqg[b * N + (jt + 1) * TJ + lane];
    }
    const unsigned short* XjHp = (const unsigned short*)XjC[jt & 1];
    const unsigned short* XjLp = (const unsigned short*)(XjC[jt & 1] + HB);
    f32x4 acc = {0, 0, 0, 0};
#pragma unroll
    for (int ks = 0; ks < C32 / 32; ++ks) {
      const int kc = ks * 32 + kb8;
      const bfrag bh = ldfragB<RB>(XjHp, 16 * ci + m15, kc);
      const bfrag bl = ldfragB<RB>(XjLp, 16 * ci + m15, kc);
      acc = mfma_bf(ah[ks], bh, acc);
      acc = mfma_bf(ah[ks], bl, acc);
      acc = mfma_bf(al[ks], bh, acc);
    }
#pragma unroll
    for (int r = 0; r < 4; ++r)
      S[jt & 1][16 * ri + (lane >> 4) * 4 + r][16 * ci + m15] = acc[r];

    if (jt > 0) select_tile(jt - 1, sq_prev);  // lagged: other S buffer

    sq_prev = sq_cur; sq_cur = sq_next;
    __syncthreads();   // single barrier: S[jt&1] complete + stage(jt+1) drained
  }
  select_tile(NT - 1, sq_prev);

  if (lane < TK) {
#pragma unroll
    for (int d = 0; d < 4; ++d) {
      const int i = i0 + 4 * w + d;
      idx_out[((size_t)b * N + i) * TK + lane] = tix[d];
    }
  }
}

// ---------------- edgeconv: gather + fp16 MFMA + BN + LeakyReLU + max_k --------
// grid: b(16) x n-tile(128) = 2048 blocks; y contiguous [16][2048][64]
template<int C, int C32>
__global__ __launch_bounds__(256)
void conv_kernel(const float* __restrict__ xA, const float* __restrict__ xB,
                 const int* __restrict__ idxg,
                 const float* __restrict__ W, const float* __restrict__ gam,
                 const float* __restrict__ bet, const float* __restrict__ mea,
                 const float* __restrict__ var, float* __restrict__ y) {
  constexpr int N = 2048, TK = 20, O = 64;
  constexpr int RB = C32 * 2;
  constexpr int CH8 = C32 / 8;
  const int b    = blockIdx.x >> 7;        // 0..15
  const int n0   = (blockIdx.x & 127) * 16;
  const int tid  = threadIdx.x;
  const int lane = tid & 63;
  const int w    = tid >> 6;

  __shared__ float    ctrF[16][C];
  __shared__ _Float16 A1[320 * C32];
  __shared__ _Float16 CtrB[16 * C32];
  __shared__ _Float16 WdT[O * C32];
  __shared__ _Float16 WcT[O * C32];

  const float* xb = xbase<C>(xA, xB, b);

  for (int i = tid; i < 16 * C; i += 256)
    ctrF[i / C][i % C] = xb[(size_t)(n0 + i / C) * C + (i % C)];

  for (int i = tid; i < O * CH8; i += 256) {
    const int o = i / CH8, ch = (i % CH8) * 8;
    hfrag hd, hc;
#pragma unroll
    for (int e = 0; e < 8; ++e) {
      const int c = ch + e;
      hd[e] = (c < C) ? (_Float16)W[o * 2 * C + c]     : (_Float16)0.f;
      hc[e] = (c < C) ? (_Float16)W[o * 2 * C + C + c] : (_Float16)0.f;
    }
    const unsigned off = swz<RB>(o, ch * 2);
    *(hfrag*)((char*)WdT + off) = hd;
    *(hfrag*)((char*)WcT + off) = hc;
  }
  __syncthreads();

  for (int i = tid; i < 16 * CH8; i += 256) {
    const int row = i / CH8, ch = (i % CH8) * 8;
    hfrag hv;
#pragma unroll
    for (int e = 0; e < 8; ++e) {
      const int c = ch + e;
      hv[e] = (c < C) ? (_Float16)ctrF[row][c] : (_Float16)0.f;
    }
    *(hfrag*)((char*)CtrB + swz<RB>(row, ch * 2)) = hv;
  }

  for (int r = tid; r < 16 * TK; r += 256) {
    const int n = r & 15, k = r >> 4;
    int j = idxg[((size_t)b * N + n0 + n) * TK + k];
    j &= (N - 1);  // safety clamp
    const float* xj = xb + (size_t)j * C;
#pragma unroll
    for (int ch = 0; ch < C32; ch += 8) {
      float f[8];
#pragma unroll
      for (int q = 0; q < 8; q += 4) {
        const int c = ch + q;
        if (c + 3 < C) {
          *(f4v*)(f + q) = *(const f4v*)(xj + c);
        } else {
#pragma unroll
          for (int e = 0; e < 4; ++e) f[q + e] = (c + e < C) ? xj[c + e] : 0.f;
        }
      }
      hfrag hv;
#pragma unroll
      for (int e = 0; e < 8; ++e) {
        const int c = ch + e;
        const float d = (c < C) ? (f[e] - ctrF[n][c]) : 0.f;
        hv[e] = (_Float16)d;
      }
      *(hfrag*)((char*)A1 + swz<RB>(r, ch * 2)) = hv;
    }
  }
  __syncthreads();

  const int m15 = lane & 15;
  const int kb8 = (lane >> 4) * 8;
  hfrag bd[C32 / 32], bc[C32 / 32];
#pragma unroll
  for (int ks = 0; ks < C32 / 32; ++ks) {
    bd[ks] = ldfragH<RB>(WdT, 16 * w + m15, ks * 32 + kb8);
    bc[ks] = ldfragH<RB>(WcT, 16 * w + m15, ks * 32 + kb8);
  }
  f32x4 base = {0, 0, 0, 0};
#pragma unroll
  for (int ks = 0; ks < C32 / 32; ++ks)
    base = mfma_h(ldfragH<RB>(CtrB, m15, ks * 32 + kb8), bc[ks], base);

  f32x4 mx = {-FLT_MAX, -FLT_MAX, -FLT_MAX, -FLT_MAX};
#pragma unroll
  for (int k = 0; k < TK; ++k) {
    f32x4 a = {0, 0, 0, 0};
#pragma unroll
    for (int ks = 0; ks < C32 / 32; ++ks)
      a = mfma_h(ldfragH<RB>(A1, 16 * k + m15, ks * 32 + kb8), bd[ks], a);
#pragma unroll
    for (int r = 0; r < 4; ++r) mx[r] = fmaxf(mx[r], a[r] + base[r]);
  }

  const int o = 16 * w + m15;
  const float scv = gam[o] / sqrtf(var[o] + 1e-5f);
  const float shv = bet[o] - mea[o] * scv;
#pragma unroll
  for (int r = 0; r < 4; ++r) {
    const int n = (lane >> 4) * 4 + r;
    float v = scv * mx[r] + shv;
    v = (v >= 0.f) ? v : 0.2f * v;
    y[((size_t)b * N + n0 + n) * O + o] = v;
  }
}

// ---------------- attention pooling (16 batches, contiguous emb) -------------
__global__ __launch_bounds__(256)
void att_mean_kernel(const float* __restrict__ emb, float* __restrict__ msum) {
  constexpr int N = 2048, F = 64;
  const int b    = blockIdx.x >> 4;          // 0..15
  const int slab = blockIdx.x & 15;          // 128 rows per slab
  const int tid  = threadIdx.x;
  const int f = tid & 63, p = tid >> 6;
  __shared__ float part[4][F];
  float acc = 0.f;
  const float* e = emb + ((size_t)b * N + slab * 128) * F;
  for (int n = p; n < 128; n += 4) acc += e[(size_t)n * F + f];
  part[p][f] = acc;
  __syncthreads();
  if (tid < F)
    atomicAdd(&msum[b * F + tid],
              part[0][tid] + part[1][tid] + part[2][tid] + part[3][tid]);
}

__global__ __launch_bounds__(64)
void att_ctx_kernel(const float* __restrict__ msum, const float* __restrict__ Watt,
                    float* __restrict__ ctx) {
  constexpr int N = 2048, F = 64;
  const int b = blockIdx.x, tid = threadIdx.x;
  __shared__ float m[F];
  m[tid] = msum[b * F + tid] * (1.f / N);
  __syncthreads();
  float a = 0.f;
  for (int ff = 0; ff < F; ++ff) a += m[ff] * Watt[ff * F + tid];
  ctx[b * F + tid] = tanhf(a);
}

__global__ __launch_bounds__(256)
void att2_kernel(const float* __restrict__ emb, const float* __restrict__ ctx,
                 float* __restrict__ eout) {
  constexpr int N = 2048, F = 64;
  const int b   = blockIdx.x >> 3;           // 0..15
  const int c0  = (blockIdx.x & 7) * 256;
  const int tid = threadIdx.x, lane = tid & 63, w = tid >> 6;
  const float cv = ctx[b * F + lane];
  float acc = 0.f;
  const float* e = emb + (size_t)b * N * F;
  for (int n = c0 + w * 64; n < c0 + (w + 1) * 64; ++n) {
    const float v = e[(size_t)n * F + lane];
    float d = v * cv;
#pragma unroll
    for (int off = 1; off < 64; off <<= 1) d += __shfl_xor(d, off);
    const float s = 1.f / (1.f + expf(-d));
    acc += v * s;
  }
  atomicAdd(&eout[b * F + lane], acc);
}

// ---------------- tensor network ----------------
__global__ __launch_bounds__(256)
void tn_kernel(const float* __restrict__ ep,
               const float* __restrict__ Wt, const float* __restrict__ Wb,
               const float* __restrict__ bias, float* __restrict__ out) {
  constexpr int F = 64, T = 16;
  const int b = blockIdx.x, tid = threadIdx.x;
  __shared__ float s1[F], s2[F];
  __shared__ float part[T][17];
  if (tid < F) { s1[tid] = ep[b * F + tid]; s2[tid] = ep[(b + 8) * F + tid]; }
  __syncthreads();
  const int t = tid >> 4, sub = tid & 15;
  float a = 0.f;
  for (int f = sub * 4; f < sub * 4 + 4; ++f) {
    float inner = 0.f;
    for (int g = 0; g < F; ++g) inner += Wt[((f * F) + g) * T + t] * s2[g];
    a += s1[f] * inner;
  }
  part[t][sub] = a;
  __syncthreads();
  if (tid < T) {
    float v = 0.f;
    for (int q = 0; q < 16; ++q) v += part[tid][q];
    for (int f = 0; f < F; ++f)
      v += Wb[tid * 2 * F + f] * s1[f] + Wb[tid * 2 * F + F + f] * s2[f];
    v += bias[tid];
    out[b * T + tid] = fmaxf(v, 0.f);
  }
}

extern "C" void kernel_launch(void* const* d_in, const int* in_sizes, int n_in,
                              void* d_out, int out_size, void* d_ws, size_t ws_size,
                              hipStream_t stream) {
  const float* x1  = (const float*)d_in[0];
  const float* x2  = (const float*)d_in[1];
  const float* W1  = (const float*)d_in[2];
  const float* g1  = (const float*)d_in[3];
  const float* b1  = (const float*)d_in[4];
  const float* m1  = (const float*)d_in[5];
  const float* v1  = (const float*)d_in[6];
  const float* W2  = (const float*)d_in[7];
  const float* g2  = (const float*)d_in[8];
  const float* b2  = (const float*)d_in[9];
  const float* m2  = (const float*)d_in[10];
  const float* v2  = (const float*)d_in[11];
  const float* W3  = (const float*)d_in[12];
  const float* g3  = (const float*)d_in[13];
  const float* b3  = (const float*)d_in[14];
  const float* m3  = (const float*)d_in[15];
  const float* v3  = (const float*)d_in[16];
  const float* Wat = (const float*)d_in[17];
  const float* Wt  = (const float*)d_in[18];
  const float* Wb  = (const float*)d_in[19];
  const float* bs  = (const float*)d_in[20];
  float* out = (float*)d_out;

  constexpr size_t NF = (size_t)16 * 2048 * 64;   // 16 batches (both graphs)
  constexpr size_t XHLB = (size_t)16 * 32 * 16384;  // max tile-image bytes (C32=64)
  float* bufA = (float*)d_ws;
  float* bufB = bufA + NF;
  float* sqb  = bufB + NF;                        // 16*2048
  int*   idxb = (int*)(sqb + 16 * 2048);          // 16*2048*20
  char*  xhl  = (char*)(idxb + (size_t)16 * 2048 * 20);   // 8 MB
  float* msum = (float*)(xhl + XHLB);             // 16*64
  float* epool= msum + 16 * 64;                   // 16*64
  float* ctx  = epool + 16 * 64;                  // 16*64

  const float* bA8 = bufA + (size_t)8 * 2048 * 64;
  const float* bB8 = bufB + (size_t)8 * 2048 * 64;

  // layer 1: x(pair) -> bufA
  sq_kernel<12><<<128, 256, 0, stream>>>(x1, x2, sqb);
  cvt_kernel<12, 32><<<512, 256, 0, stream>>>(x1, x2, xhl);
  knn_kernel<32><<<1024, 512, 0, stream>>>(xhl, sqb, idxb);
  conv_kernel<12, 32><<<2048, 256, 0, stream>>>(x1, x2, idxb, W1, g1, b1, m1, v1, bufA);

  // layer 2: bufA -> bufB
  sq_kernel<64><<<128, 256, 0, stream>>>(bufA, bA8, sqb);
  cvt_kernel<64, 64><<<1024, 256, 0, stream>>>(bufA, bA8, xhl);
  knn_kernel<64><<<1024, 512, 0, stream>>>(xhl, sqb, idxb);
  conv_kernel<64, 64><<<2048, 256, 0, stream>>>(bufA, bA8, idxb, W2, g2, b2, m2, v2, bufB);

  // layer 3: bufB -> bufA (= final emb, 16 batches)
  sq_kernel<64><<<128, 256, 0, stream>>>(bufB, bB8, sqb);
  cvt_kernel<64, 64><<<1024, 256, 0, stream>>>(bufB, bB8, xhl);
  knn_kernel<64><<<1024, 512, 0, stream>>>(xhl, sqb, idxb);
  conv_kernel<64, 64><<<2048, 256, 0, stream>>>(bufB, bB8, idxb, W3, g3, b3, m3, v3, bufA);

  hipMemsetAsync(msum, 0, 2 * 16 * 64 * sizeof(float), stream);  // msum+epool
  att_mean_kernel<<<256, 256, 0, stream>>>(bufA, msum);
  att_ctx_kernel<<<16, 64, 0, stream>>>(msum, Wat, ctx);
  att2_kernel<<<128, 256, 0, stream>>>(bufA, ctx, epool);
  tn_kernel<<<8, 256, 0, stream>>>(epool, Wt, Wb, bs, out);
}

// Round 10
// 919.568 us; speedup vs baseline: 1.0304x; 1.0304x over previous
//
#include <hip/hip_runtime.h>
#include <hip/hip_bf16.h>
#include <float.h>

#define DEV __device__ __forceinline__

using f32x4 = __attribute__((ext_vector_type(4))) float;
using f4v   = __attribute__((ext_vector_type(4))) float;
using bfrag = __attribute__((ext_vector_type(8))) short;     // 8 bf16
using hfrag = __attribute__((ext_vector_type(8))) _Float16;  // 8 f16
using us8   = __attribute__((ext_vector_type(8))) unsigned short;

DEV unsigned short f2bf(float f) {
  unsigned u = __builtin_bit_cast(unsigned, f);
  u += 0x7FFFu + ((u >> 16) & 1u);
  return (unsigned short)(u >> 16);
}
DEV float bf2f(unsigned short h) {
  unsigned u = ((unsigned)h) << 16;
  return __builtin_bit_cast(float, u);
}
DEV f32x4 mfma_bf(bfrag a, bfrag b, f32x4 c) {
  return __builtin_amdgcn_mfma_f32_16x16x32_bf16(a, b, c, 0, 0, 0);
}
DEV f32x4 mfma_h(hfrag a, hfrag b, f32x4 c) {
  return __builtin_amdgcn_mfma_f32_16x16x32_f16(a, b, c, 0, 0, 0);
}
DEV float readlane_f(float v, int l) {
  return __builtin_bit_cast(float,
      __builtin_amdgcn_readlane(__builtin_bit_cast(int, v), l));
}
// wave_shr:1 via DPP (VALU, no LDS): lane i <- lane i-1; lane 0 <- 0 (unused)
DEV int dpp_shr1_i(int v) {
  return __builtin_amdgcn_update_dpp(0, v, 0x138, 0xf, 0xf, false);
}
DEV float dpp_shr1_f(float v) {
  return __builtin_bit_cast(float,
      __builtin_amdgcn_update_dpp(0, __builtin_bit_cast(int, v),
                                  0x138, 0xf, 0xf, false));
}
// async global->LDS, 16B per lane; LDS dest must be wave-uniform base + lane*16
DEV void glds16(const void* g, void* l) {
  __builtin_amdgcn_global_load_lds(
      (const __attribute__((address_space(1))) void*)g,
      (__attribute__((address_space(3))) void*)l, 16, 0, 0);
}
template<int BYTES>
DEV void gldsN(const char* __restrict__ g, char* __restrict__ l, int tid) {
  if constexpr (BYTES >= 8192) {
#pragma unroll
    for (int o = 0; o < BYTES; o += 8192)
      glds16(g + o + tid * 16, l + o + tid * 16);
  } else {
    if (tid * 16 < BYTES) glds16(g + tid * 16, l + tid * 16);  // full waves only
  }
}

// XOR-swizzled LDS byte offset for row-major tiles of RB bytes/row (T2 pattern)
template<int RB>
DEV unsigned swz(int row, int colb) {
  return (unsigned)(row * RB) +
         (((unsigned)colb) ^ (((unsigned)(row << 4)) & (unsigned)(RB - 1)));
}
template<int RB>
DEV bfrag ldfragB(const unsigned short* base, int row, int kcol) {
  return *(const bfrag*)((const char*)base + swz<RB>(row, kcol * 2));
}
template<int RB>
DEV hfrag ldfragH(const _Float16* base, int row, int kcol) {
  return *(const hfrag*)((const char*)base + swz<RB>(row, kcol * 2));
}

// full-wave bitonic sort, descending by value, ties ascending by index
DEV void bitonic64(float& v, int& ix, int lane) {
#pragma unroll
  for (int k = 2; k <= 64; k <<= 1) {
#pragma unroll
    for (int j = k >> 1; j > 0; j >>= 1) {
      const float ov = __shfl_xor(v, j);
      const int   oi = __shfl_xor(ix, j);
      const bool up = (lane & k) != 0;
      const bool iWin = (v > ov) || (v == ov && ix < oi);
      const bool keepBetter = (((lane & j) == 0) != up);
      if (iWin != keepBetter) { v = ov; ix = oi; }
    }
  }
}

// batch selector: b in 0..15 -> graph1 (xA) batches 0..7, graph2 (xB) 8..15
template<int C>
DEV const float* xbase(const float* xA, const float* xB, int b) {
  return (b < 8) ? xA + (size_t)b * 2048 * C
                 : xB + (size_t)(b - 8) * 2048 * C;
}

// ---------------- squared norms (16 batches, pair input) ----------------
template<int C>
__global__ __launch_bounds__(256)
void sq_kernel(const float* __restrict__ xA, const float* __restrict__ xB,
               float* __restrict__ sq) {
  const int i = blockIdx.x * 256 + threadIdx.x;   // 0 .. 16*2048-1
  const int b = i >> 11, n = i & 2047;
  const float* r = xbase<C>(xA, xB, b) + (size_t)n * C;
  float s = 0.f;
#pragma unroll
  for (int c = 0; c < C; c += 4) {
    f4v v = *(const f4v*)(r + c);
    s += v[0] * v[0] + v[1] * v[1] + v[2] * v[2] + v[3] * v[3];
  }
  sq[i] = s;
}

// ---------------- one-time fp32 -> bf16 hi/lo pre-swizzled tile images --------
// layout: [b(16)][tile(32)][ H: 64 rows x C32 bf16 swizzled | L: same ]
template<int C, int C32>
__global__ __launch_bounds__(256)
void cvt_kernel(const float* __restrict__ xA, const float* __restrict__ xB,
                char* __restrict__ xhl) {
  constexpr int CH8 = C32 / 8, RB = C32 * 2, HB = 64 * RB;
  const int idx = blockIdx.x * 256 + threadIdx.x;
  const int chunk = idx & (CH8 - 1);
  const int rg = idx / CH8;
  const int b = rg >> 11, n = rg & 2047;
  const float* src = xbase<C>(xA, xB, b) + (size_t)n * C;
  const int cb = chunk * 8;
  float f[8];
  if constexpr (C % 8 == 0) {
    *(f4v*)(f + 0) = *(const f4v*)(src + cb);
    *(f4v*)(f + 4) = *(const f4v*)(src + cb + 4);
  } else {
#pragma unroll
    for (int e = 0; e < 8; ++e) {
      const int c = cb + e;
      f[e] = (c < C) ? src[c] : 0.f;
    }
  }
  us8 hv, lv;
#pragma unroll
  for (int e = 0; e < 8; ++e) {
    const unsigned short hs = f2bf(f[e]);
    hv[e] = hs;
    lv[e] = f2bf(f[e] - bf2f(hs));
  }
  char* dst = xhl + (size_t)(b * 32 + (n >> 6)) * 2 * HB;
  const unsigned off = swz<RB>(n & 63, cb * 2);
  *(us8*)(dst + off) = hv;
  *(us8*)(dst + HB + off) = lv;
}

// ---------------- fused kNN: pipelined, 1 barrier/tile, lagged selection ------
// grid: b(16) x i-tile(64, 32 rows) = 1024 blocks, 512 threads (8 waves).
// Insert chain uses DPP wave_shr:1 (VALU) instead of shfl_up (DS) -> ~5x
// shorter dependent latency per insert.
template<int C32>
__global__ __launch_bounds__(512)
void knn_kernel(const char* __restrict__ xhl, const float* __restrict__ sqg,
                int* __restrict__ idx_out) {
  constexpr int N = 2048, TI = 32, TJ = 64, TK = 20, NT = N / TJ;
  constexpr int RB = C32 * 2, HB = 64 * RB, TILEB = 2 * HB, HBi = TI * RB;
  const int b    = blockIdx.x >> 6;        // 0..15
  const int it   = blockIdx.x & 63;        // 32-row i-tile
  const int i0   = it * TI;
  const int tid  = threadIdx.x;
  const int lane = tid & 63;
  const int w    = tid >> 6;               // 0..7
  const int ri   = w >> 2;                 // 0..1
  const int ci   = w & 3;                  // 0..3

  __shared__ char XiC[2 * HBi];
  __shared__ char XjC[2][TILEB];
  __shared__ float S[2][TI][TJ + 4];

  const unsigned short* XiHp = (const unsigned short*)XiC;
  const unsigned short* XiLp = (const unsigned short*)(XiC + HBi);
  const int m15 = lane & 15, kb8 = (lane >> 4) * 8;

  const char* gbt = xhl + (size_t)(b * 32) * TILEB;
  const char* gti = gbt + (size_t)(i0 >> 6) * TILEB + (i0 & 63) * RB;
  gldsN<HBi>(gti, XiC, tid);            // Xi H slice (contiguous rows)
  gldsN<HBi>(gti + HB, XiC + HBi, tid); // Xi L slice
  gldsN<TILEB>(gbt, XjC[0], tid);       // tile 0
  float sq_cur = sqg[b * N + lane];     // sq of tile 0 (register)
  float sq_prev = 0.f;
  __syncthreads();                      // drains vmcnt: Xi + Xj0 staged

  // Xi fragments are loop-invariant -> registers
  bfrag ah[C32 / 32], al[C32 / 32];
#pragma unroll
  for (int ks = 0; ks < C32 / 32; ++ks) {
    ah[ks] = ldfragB<RB>(XiHp, 16 * ri + m15, ks * 32 + kb8);
    al[ks] = ldfragB<RB>(XiLp, 16 * ri + m15, ks * 32 + kb8);
  }

  float tv[4], t20[4]; int tix[4];
#pragma unroll
  for (int d = 0; d < 4; ++d) { tv[d] = -FLT_MAX; tix[d] = 0; t20[d] = -FLT_MAX; }

  // selection for tile jts (S buffer jts&1), sqv = sq of tile jts
  auto select_tile = [&](int jts, float sqv) {
    const int j0 = jts * TJ;
    const float (*Sb)[TJ + 4] = S[jts & 1];
#pragma unroll
    for (int d = 0; d < 4; ++d) {
      const float sc = 2.f * Sb[4 * w + d][lane] - sqv;
      if (jts == 0) {
        float v = sc; int ixv = lane;    // j0 == 0
        bitonic64(v, ixv, lane);
        tv[d]  = (lane < TK) ? v : -FLT_MAX;
        tix[d] = (lane < TK) ? ixv : 0;
        t20[d] = readlane_f(tv[d], TK - 1);
      } else {
        unsigned long long mm = __ballot(sc > t20[d]);
        if (mm) {
          while (mm) {
            const int src = __ffsll(mm) - 1;
            mm &= mm - 1;
            const float cv = readlane_f(sc, src);
            const int   ci2 = j0 + src;
            const float pv_ = dpp_shr1_f(tv[d]);   // lane-1 value (VALU DPP)
            const int   pi_ = dpp_shr1_i(tix[d]);  // lane-1 index (VALU DPP)
            const unsigned long long g =
                __ballot(tv[d] > cv || (tv[d] == cv && tix[d] < ci2));
            const int p = __popcll(g);     // wave-uniform
            float nv = (lane == p) ? cv  : ((lane > p) ? pv_ : tv[d]);
            int   ni = (lane == p) ? ci2 : ((lane > p) ? pi_ : tix[d]);
            tv[d]  = (lane >= TK) ? -FLT_MAX : nv;
            tix[d] = (lane >= TK) ? 0 : ni;
          }
          t20[d] = readlane_f(tv[d], TK - 1);  // refresh once per tile
        }
      }
    }
  };

  for (int jt = 0; jt < NT; ++jt) {
    float sq_next = 0.f;
    if (jt + 1 < NT) {   // issue next-tile stage early (hidden under MFMA+select)
      gldsN<TILEB>(gbt + (size_t)(jt + 1) * TILEB, XjC[(jt + 1) & 1], tid);
      sq_next = sqg[b * N + (jt + 1) * TJ + lane];
    }
    const unsigned short* XjHp = (const unsigned short*)XjC[jt & 1];
    const unsigned short* XjLp = (const unsigned short*)(XjC[jt & 1] + HB);
    f32x4 acc = {0, 0, 0, 0};
#pragma unroll
    for (int ks = 0; ks < C32 / 32; ++ks) {
      const int kc = ks * 32 + kb8;
      const bfrag bh = ldfragB<RB>(XjHp, 16 * ci + m15, kc);
      const bfrag bl = ldfragB<RB>(XjLp, 16 * ci + m15, kc);
      acc = mfma_bf(ah[ks], bh, acc);
      acc = mfma_bf(ah[ks], bl, acc);
      acc = mfma_bf(al[ks], bh, acc);
    }
#pragma unroll
    for (int r = 0; r < 4; ++r)
      S[jt & 1][16 * ri + (lane >> 4) * 4 + r][16 * ci + m15] = acc[r];

    if (jt > 0) select_tile(jt - 1, sq_prev);  // lagged: other S buffer

    sq_prev = sq_cur; sq_cur = sq_next;
    __syncthreads();   // single barrier: S[jt&1] complete + stage(jt+1) drained
  }
  select_tile(NT - 1, sq_prev);

  if (lane < TK) {
#pragma unroll
    for (int d = 0; d < 4; ++d) {
      const int i = i0 + 4 * w + d;
      idx_out[((size_t)b * N + i) * TK + lane] = tix[d];
    }
  }
}

// ---------------- edgeconv: gather + fp16 MFMA + BN + LeakyReLU + max_k --------
// grid: b(16) x n-tile(128) = 2048 blocks; y contiguous [16][2048][64]
template<int C, int C32>
__global__ __launch_bounds__(256)
void conv_kernel(const float* __restrict__ xA, const float* __restrict__ xB,
                 const int* __restrict__ idxg,
                 const float* __restrict__ W, const float* __restrict__ gam,
                 const float* __restrict__ bet, const float* __restrict__ mea,
                 const float* __restrict__ var, float* __restrict__ y) {
  constexpr int N = 2048, TK = 20, O = 64;
  constexpr int RB = C32 * 2;
  constexpr int CH8 = C32 / 8;
  const int b    = blockIdx.x >> 7;        // 0..15
  const int n0   = (blockIdx.x & 127) * 16;
  const int tid  = threadIdx.x;
  const int lane = tid & 63;
  const int w    = tid >> 6;

  __shared__ float    ctrF[16][C];
  __shared__ _Float16 A1[320 * C32];
  __shared__ _Float16 CtrB[16 * C32];
  __shared__ _Float16 WdT[O * C32];
  __shared__ _Float16 WcT[O * C32];

  const float* xb = xbase<C>(xA, xB, b);

  for (int i = tid; i < 16 * C; i += 256)
    ctrF[i / C][i % C] = xb[(size_t)(n0 + i / C) * C + (i % C)];

  for (int i = tid; i < O * CH8; i += 256) {
    const int o = i / CH8, ch = (i % CH8) * 8;
    hfrag hd, hc;
#pragma unroll
    for (int e = 0; e < 8; ++e) {
      const int c = ch + e;
      hd[e] = (c < C) ? (_Float16)W[o * 2 * C + c]     : (_Float16)0.f;
      hc[e] = (c < C) ? (_Float16)W[o * 2 * C + C + c] : (_Float16)0.f;
    }
    const unsigned off = swz<RB>(o, ch * 2);
    *(hfrag*)((char*)WdT + off) = hd;
    *(hfrag*)((char*)WcT + off) = hc;
  }
  __syncthreads();

  for (int i = tid; i < 16 * CH8; i += 256) {
    const int row = i / CH8, ch = (i % CH8) * 8;
    hfrag hv;
#pragma unroll
    for (int e = 0; e < 8; ++e) {
      const int c = ch + e;
      hv[e] = (c < C) ? (_Float16)ctrF[row][c] : (_Float16)0.f;
    }
    *(hfrag*)((char*)CtrB + swz<RB>(row, ch * 2)) = hv;
  }

  for (int r = tid; r < 16 * TK; r += 256) {
    const int n = r & 15, k = r >> 4;
    int j = idxg[((size_t)b * N + n0 + n) * TK + k];
    j &= (N - 1);  // safety clamp
    const float* xj = xb + (size_t)j * C;
#pragma unroll
    for (int ch = 0; ch < C32; ch += 8) {
      float f[8];
#pragma unroll
      for (int q = 0; q < 8; q += 4) {
        const int c = ch + q;
        if (c + 3 < C) {
          *(f4v*)(f + q) = *(const f4v*)(xj + c);
        } else {
#pragma unroll
          for (int e = 0; e < 4; ++e) f[q + e] = (c + e < C) ? xj[c + e] : 0.f;
        }
      }
      hfrag hv;
#pragma unroll
      for (int e = 0; e < 8; ++e) {
        const int c = ch + e;
        const float d = (c < C) ? (f[e] - ctrF[n][c]) : 0.f;
        hv[e] = (_Float16)d;
      }
      *(hfrag*)((char*)A1 + swz<RB>(r, ch * 2)) = hv;
    }
  }
  __syncthreads();

  const int m15 = lane & 15;
  const int kb8 = (lane >> 4) * 8;
  hfrag bd[C32 / 32], bc[C32 / 32];
#pragma unroll
  for (int ks = 0; ks < C32 / 32; ++ks) {
    bd[ks] = ldfragH<RB>(WdT, 16 * w + m15, ks * 32 + kb8);
    bc[ks] = ldfragH<RB>(WcT, 16 * w + m15, ks * 32 + kb8);
  }
  f32x4 base = {0, 0, 0, 0};
#pragma unroll
  for (int ks = 0; ks < C32 / 32; ++ks)
    base = mfma_h(ldfragH<RB>(CtrB, m15, ks * 32 + kb8), bc[ks], base);

  f32x4 mx = {-FLT_MAX, -FLT_MAX, -FLT_MAX, -FLT_MAX};
#pragma unroll
  for (int k = 0; k < TK; ++k) {
    f32x4 a = {0, 0, 0, 0};
#pragma unroll
    for (int ks = 0; ks < C32 / 32; ++ks)
      a = mfma_h(ldfragH<RB>(A1, 16 * k + m15, ks * 32 + kb8), bd[ks], a);
#pragma unroll
    for (int r = 0; r < 4; ++r) mx[r] = fmaxf(mx[r], a[r] + base[r]);
  }

  const int o = 16 * w + m15;
  const float scv = gam[o] / sqrtf(var[o] + 1e-5f);
  const float shv = bet[o] - mea[o] * scv;
#pragma unroll
  for (int r = 0; r < 4; ++r) {
    const int n = (lane >> 4) * 4 + r;
    float v = scv * mx[r] + shv;
    v = (v >= 0.f) ? v : 0.2f * v;
    y[((size_t)b * N + n0 + n) * O + o] = v;
  }
}

// ---------------- attention pooling (16 batches, contiguous emb) -------------
__global__ __launch_bounds__(256)
void att_mean_kernel(const float* __restrict__ emb, float* __restrict__ msum) {
  constexpr int N = 2048, F = 64;
  const int b    = blockIdx.x >> 4;          // 0..15
  const int slab = blockIdx.x & 15;          // 128 rows per slab
  const int tid  = threadIdx.x;
  const int f = tid & 63, p = tid >> 6;
  __shared__ float part[4][F];
  float acc = 0.f;
  const float* e = emb + ((size_t)b * N + slab * 128) * F;
  for (int n = p; n < 128; n += 4) acc += e[(size_t)n * F + f];
  part[p][f] = acc;
  __syncthreads();
  if (tid < F)
    atomicAdd(&msum[b * F + tid],
              part[0][tid] + part[1][tid] + part[2][tid] + part[3][tid]);
}

__global__ __launch_bounds__(64)
void att_ctx_kernel(const float* __restrict__ msum, const float* __restrict__ Watt,
                    float* __restrict__ ctx) {
  constexpr int N = 2048, F = 64;
  const int b = blockIdx.x, tid = threadIdx.x;
  __shared__ float m[F];
  m[tid] = msum[b * F + tid] * (1.f / N);
  __syncthreads();
  float a = 0.f;
  for (int ff = 0; ff < F; ++ff) a += m[ff] * Watt[ff * F + tid];
  ctx[b * F + tid] = tanhf(a);
}

__global__ __launch_bounds__(256)
void att2_kernel(const float* __restrict__ emb, const float* __restrict__ ctx,
                 float* __restrict__ eout) {
  constexpr int N = 2048, F = 64;
  const int b   = blockIdx.x >> 3;           // 0..15
  const int c0  = (blockIdx.x & 7) * 256;
  const int tid = threadIdx.x, lane = tid & 63, w = tid >> 6;
  const float cv = ctx[b * F + lane];
  float acc = 0.f;
  const float* e = emb + (size_t)b * N * F;
  for (int n = c0 + w * 64; n < c0 + (w + 1) * 64; ++n) {
    const float v = e[(size_t)n * F + lane];
    float d = v * cv;
#pragma unroll
    for (int off = 1; off < 64; off <<= 1) d += __shfl_xor(d, off);
    const float s = 1.f / (1.f + expf(-d));
    acc += v * s;
  }
  atomicAdd(&eout[b * F + lane], acc);
}

// ---------------- tensor network ----------------
__global__ __launch_bounds__(256)
void tn_kernel(const float* __restrict__ ep,
               const float* __restrict__ Wt, const float* __restrict__ Wb,
               const float* __restrict__ bias, float* __restrict__ out) {
  constexpr int F = 64, T = 16;
  const int b = blockIdx.x, tid = threadIdx.x;
  __shared__ float s1[F], s2[F];
  __shared__ float part[T][17];
  if (tid < F) { s1[tid] = ep[b * F + tid]; s2[tid] = ep[(b + 8) * F + tid]; }
  __syncthreads();
  const int t = tid >> 4, sub = tid & 15;
  float a = 0.f;
  for (int f = sub * 4; f < sub * 4 + 4; ++f) {
    float inner = 0.f;
    for (int g = 0; g < F; ++g) inner += Wt[((f * F) + g) * T + t] * s2[g];
    a += s1[f] * inner;
  }
  part[t][sub] = a;
  __syncthreads();
  if (tid < T) {
    float v = 0.f;
    for (int q = 0; q < 16; ++q) v += part[tid][q];
    for (int f = 0; f < F; ++f)
      v += Wb[tid * 2 * F + f] * s1[f] + Wb[tid * 2 * F + F + f] * s2[f];
    v += bias[tid];
    out[b * T + tid] = fmaxf(v, 0.f);
  }
}

extern "C" void kernel_launch(void* const* d_in, const int* in_sizes, int n_in,
                              void* d_out, int out_size, void* d_ws, size_t ws_size,
                              hipStream_t stream) {
  const float* x1  = (const float*)d_in[0];
  const float* x2  = (const float*)d_in[1];
  const float* W1  = (const float*)d_in[2];
  const float* g1  = (const float*)d_in[3];
  const float* b1  = (const float*)d_in[4];
  const float* m1  = (const float*)d_in[5];
  const float* v1  = (const float*)d_in[6];
  const float* W2  = (const float*)d_in[7];
  const float* g2  = (const float*)d_in[8];
  const float* b2  = (const float*)d_in[9];
  const float* m2  = (const float*)d_in[10];
  const float* v2  = (const float*)d_in[11];
  const float* W3  = (const float*)d_in[12];
  const float* g3  = (const float*)d_in[13];
  const float* b3  = (const float*)d_in[14];
  const float* m3  = (const float*)d_in[15];
  const float* v3  = (const float*)d_in[16];
  const float* Wat = (const float*)d_in[17];
  const float* Wt  = (const float*)d_in[18];
  const float* Wb  = (const float*)d_in[19];
  const float* bs  = (const float*)d_in[20];
  float* out = (float*)d_out;

  constexpr size_t NF = (size_t)16 * 2048 * 64;   // 16 batches (both graphs)
  constexpr size_t XHLB = (size_t)16 * 32 * 16384;  // max tile-image bytes (C32=64)
  float* bufA = (float*)d_ws;
  float* bufB = bufA + NF;
  float* sqb  = bufB + NF;                        // 16*2048
  int*   idxb = (int*)(sqb + 16 * 2048);          // 16*2048*20
  char*  xhl  = (char*)(idxb + (size_t)16 * 2048 * 20);   // 8 MB
  float* msum = (float*)(xhl + XHLB);             // 16*64
  float* epool= msum + 16 * 64;                   // 16*64
  float* ctx  = epool + 16 * 64;                  // 16*64

  const float* bA8 = bufA + (size_t)8 * 2048 * 64;
  const float* bB8 = bufB + (size_t)8 * 2048 * 64;

  // layer 1: x(pair) -> bufA
  sq_kernel<12><<<128, 256, 0, stream>>>(x1, x2, sqb);
  cvt_kernel<12, 32><<<512, 256, 0, stream>>>(x1, x2, xhl);
  knn_kernel<32><<<1024, 512, 0, stream>>>(xhl, sqb, idxb);
  conv_kernel<12, 32><<<2048, 256, 0, stream>>>(x1, x2, idxb, W1, g1, b1, m1, v1, bufA);

  // layer 2: bufA -> bufB
  sq_kernel<64><<<128, 256, 0, stream>>>(bufA, bA8, sqb);
  cvt_kernel<64, 64><<<1024, 256, 0, stream>>>(bufA, bA8, xhl);
  knn_kernel<64><<<1024, 512, 0, stream>>>(xhl, sqb, idxb);
  conv_kernel<64, 64><<<2048, 256, 0, stream>>>(bufA, bA8, idxb, W2, g2, b2, m2, v2, bufB);

  // layer 3: bufB -> bufA (= final emb, 16 batches)
  sq_kernel<64><<<128, 256, 0, stream>>>(bufB, bB8, sqb);
  cvt_kernel<64, 64><<<1024, 256, 0, stream>>>(bufB, bB8, xhl);
  knn_kernel<64><<<1024, 512, 0, stream>>>(xhl, sqb, idxb);
  conv_kernel<64, 64><<<2048, 256, 0, stream>>>(bufB, bB8, idxb, W3, g3, b3, m3, v3, bufA);

  hipMemsetAsync(msum, 0, 2 * 16 * 64 * sizeof(float), stream);  // msum+epool
  att_mean_kernel<<<256, 256, 0, stream>>>(bufA, msum);
  att_ctx_kernel<<<16, 64, 0, stream>>>(msum, Wat, ctx);
  att2_kernel<<<128, 256, 0, stream>>>(bufA, ctx, epool);
  tn_kernel<<<8, 256, 0, stream>>>(epool, Wt, Wb, bs, out);
}